// Round 3
// baseline (1529.533 us; speedup 1.0000x reference)
//
#include <hip/hip_runtime.h>

// W8A16 GEMM: out[m,n] = scale[n] * sum_k x[m,k]*Wint[n,k] + bias[n]
// M=8192, N=11008, K=4096.
// Device dtypes (schema carries fp16 as f32!): x f32, W int32 (int8 vals),
// scales f32, bias f32, out f32.
#define M_DIM 8192
#define N_DIM 11008
#define K_DIM 4096
#define BM 128
#define BN 128
#define BK 32
#define PITCH 40  // padded LDS row pitch (ushorts)

typedef __bf16 bf16x8 __attribute__((ext_vector_type(8)));
typedef float  f32x4  __attribute__((ext_vector_type(4)));
typedef int    i32x4  __attribute__((ext_vector_type(4)));
typedef unsigned short u16x8 __attribute__((ext_vector_type(8)));

__device__ __forceinline__ unsigned short f2bf_rne(float f) {
  unsigned u = __float_as_uint(f);
  u += 0x7fffu + ((u >> 16) & 1u);
  return (unsigned short)(u >> 16);
}
__device__ __forceinline__ unsigned short i2bf(int v) {
  // |v| <= 127 fits bf16's 8-bit mantissa exactly.
  float f = (float)v;
  return (unsigned short)(__float_as_uint(f) >> 16);
}

__global__ __launch_bounds__(256)
void w8a16_gemm_kernel(const float* __restrict__ X,   // [M][K] f32 (fp16 values)
                       const int*   __restrict__ W,   // [N][K] int32 (int8 vals)
                       const float* __restrict__ S,   // [N] f32 scales
                       const float* __restrict__ Bv,  // [N] f32 bias
                       float*       __restrict__ O)   // [M][N] f32
{
  __shared__ unsigned short As[BM * PITCH];
  __shared__ unsigned short Bs[BN * PITCH];

  const int tid  = threadIdx.x;
  const int lane = tid & 63;
  const int wid  = tid >> 6;       // 4 waves, 2x2
  const int wr   = wid >> 1;
  const int wc   = wid & 1;

  // XCD-chunked bijective swizzle: 5504 blocks = 8 XCDs x 688.
  // Within an XCD chunk: 8 consecutive M-tiles share one W panel (L2 reuse).
  const int p   = blockIdx.x;
  const int xcd = p & 7;
  const int seq = p >> 3;                 // 0..687
  const int bn_idx = seq >> 3;            // 0..85
  const int by_idx = xcd * 8 + (seq & 7); // 0..63
  const int row0 = by_idx * BM;
  const int col0 = bn_idx * BN;

  f32x4 acc[4][4] = {};

  // Staging: thread -> row tid>>1 (0..127), k-chunk (tid&1)*16 elements.
  const int st_row = tid >> 1;
  const int st_kc  = (tid & 1) * 16;
  const float* xsrc = X + (row0 + st_row) * K_DIM + st_kc;
  const int*   wsrc = W + (col0 + st_row) * K_DIM + st_kc;
  unsigned short* adst = &As[st_row * PITCH + st_kc];
  unsigned short* bdst = &Bs[st_row * PITCH + st_kc];

  const int fr = lane & 15;
  const int fk = (lane >> 4) * 8;

  for (int kt = 0; kt < K_DIM; kt += BK) {
    // ---- global -> regs (before barrier: overlaps other waves' MFMA) ----
    f32x4 a0 = *(const f32x4*)(xsrc + kt);
    f32x4 a1 = *(const f32x4*)(xsrc + kt + 4);
    f32x4 a2 = *(const f32x4*)(xsrc + kt + 8);
    f32x4 a3 = *(const f32x4*)(xsrc + kt + 12);
    i32x4 w0 = *(const i32x4*)(wsrc + kt);
    i32x4 w1 = *(const i32x4*)(wsrc + kt + 4);
    i32x4 w2 = *(const i32x4*)(wsrc + kt + 8);
    i32x4 w3 = *(const i32x4*)(wsrc + kt + 12);

    u16x8 pa0, pa1, pb0, pb1;
    #pragma unroll
    for (int e = 0; e < 4; ++e) {
      pa0[e]     = f2bf_rne(a0[e]);
      pa0[e + 4] = f2bf_rne(a1[e]);
      pa1[e]     = f2bf_rne(a2[e]);
      pa1[e + 4] = f2bf_rne(a3[e]);
      pb0[e]     = i2bf(w0[e]);
      pb0[e + 4] = i2bf(w1[e]);
      pb1[e]     = i2bf(w2[e]);
      pb1[e + 4] = i2bf(w3[e]);
    }

    __syncthreads();  // previous iteration's frag reads complete

    // ---- regs -> LDS ----
    *(u16x8*)(adst)     = pa0;
    *(u16x8*)(adst + 8) = pa1;
    *(u16x8*)(bdst)     = pb0;
    *(u16x8*)(bdst + 8) = pb1;

    __syncthreads();  // tiles visible to all waves

    // ---- fragments + 16 MFMA per wave ----
    bf16x8 af[4], bfr[4];
    #pragma unroll
    for (int i = 0; i < 4; ++i)
      af[i] = *(const bf16x8*)&As[(wr * 64 + i * 16 + fr) * PITCH + fk];
    #pragma unroll
    for (int j = 0; j < 4; ++j)
      bfr[j] = *(const bf16x8*)&Bs[(wc * 64 + j * 16 + fr) * PITCH + fk];
    #pragma unroll
    for (int i = 0; i < 4; ++i)
      #pragma unroll
      for (int j = 0; j < 4; ++j)
        acc[i][j] = __builtin_amdgcn_mfma_f32_16x16x32_bf16(af[i], bfr[j], acc[i][j], 0, 0, 0);
  }

  // ---- epilogue: scale + bias in fp32, store f32 ----
  // C/D layout (verified m89): col = lane&15, row = (lane>>4)*4 + e
  const int erow = (lane >> 4) * 4;
  const int ecol = lane & 15;
  #pragma unroll
  for (int j = 0; j < 4; ++j) {
    const int col = col0 + wc * 64 + j * 16 + ecol;
    const float s  = S[col];
    const float bb = Bv[col];
    #pragma unroll
    for (int i = 0; i < 4; ++i) {
      const int rbase = row0 + wr * 64 + i * 16 + erow;
      #pragma unroll
      for (int e = 0; e < 4; ++e) {
        O[(rbase + e) * N_DIM + col] = acc[i][j][e] * s + bb;
      }
    }
  }
}

extern "C" void kernel_launch(void* const* d_in, const int* in_sizes, int n_in,
                              void* d_out, int out_size, void* d_ws, size_t ws_size,
                              hipStream_t stream) {
  const float* x  = (const float*)d_in[0];
  const int*   w  = (const int*)d_in[1];
  const float* sc = (const float*)d_in[2];
  const float* bi = (const float*)d_in[3];
  float* out = (float*)d_out;

  const int grid = (M_DIM / BM) * (N_DIM / BN);  // 64 * 86 = 5504
  w8a16_gemm_kernel<<<grid, 256, 0, stream>>>(x, w, sc, bi, out);
}

// Round 4
// 990.530 us; speedup vs baseline: 1.5442x; 1.5442x over previous
//
#include <hip/hip_runtime.h>

// W8A16 GEMM: out[m,n] = scale[n] * sum_k x[m,k]*Wint[n,k] + bias[n]
// M=8192, N=11008, K=4096.
// Device dtypes (schema carries fp16 as f32): x f32, W int32 (int8 vals),
// scales f32, bias f32, out f32.
// Round 4: prepass dequant (W->bf16, X->bf16 in d_ws) + m97-structure bf16 GEMM
// (128x128 tile, BK=32, linear LDS, global_load_lds width=16, 2 barriers/K-step).
#define M_DIM 8192
#define N_DIM 11008
#define K_DIM 4096
#define BM 128
#define BN 128
#define BK 32

typedef __bf16 bf16x8 __attribute__((ext_vector_type(8)));
typedef float  f32x4  __attribute__((ext_vector_type(4)));
typedef int    i32x4  __attribute__((ext_vector_type(4)));
typedef unsigned short u16x8 __attribute__((ext_vector_type(8)));

__device__ __forceinline__ unsigned short f2bf_rne(float f) {
  unsigned u = __float_as_uint(f);
  u += 0x7fffu + ((u >> 16) & 1u);
  return (unsigned short)(u >> 16);
}
__device__ __forceinline__ unsigned short i2bf(int v) {
  // |v| <= 127 fits bf16's 8-bit mantissa exactly.
  float f = (float)v;
  return (unsigned short)(__float_as_uint(f) >> 16);
}
__device__ __forceinline__ void async_copy16(void* lds_dst, const void* g_src) {
  __builtin_amdgcn_global_load_lds(
      (const __attribute__((address_space(1))) void*)g_src,
      (__attribute__((address_space(3))) void*)lds_dst,
      16, 0, 0);
}

// ---------------- prepass: W int32 -> bf16 (exact) ----------------
__global__ __launch_bounds__(256)
void dequant_w_kernel(const int* __restrict__ W, unsigned short* __restrict__ Wb) {
  const int NG = N_DIM * K_DIM / 8;  // 5,636,096 groups of 8
  for (int g = blockIdx.x * 256 + threadIdx.x; g < NG; g += gridDim.x * 256) {
    const int* p = W + g * 8;
    i32x4 w0 = *(const i32x4*)p;
    i32x4 w1 = *(const i32x4*)(p + 4);
    u16x8 o;
    #pragma unroll
    for (int e = 0; e < 4; ++e) {
      o[e]     = i2bf(w0[e]);
      o[e + 4] = i2bf(w1[e]);
    }
    *(u16x8*)(Wb + g * 8) = o;
  }
}

// ---------------- prepass: X f32 -> bf16 (RNE) ----------------
__global__ __launch_bounds__(256)
void conv_x_kernel(const float* __restrict__ X, unsigned short* __restrict__ Xb) {
  const int NG = M_DIM * K_DIM / 8;  // 4,194,304 groups of 8
  for (int g = blockIdx.x * 256 + threadIdx.x; g < NG; g += gridDim.x * 256) {
    const float* p = X + g * 8;
    f32x4 a0 = *(const f32x4*)p;
    f32x4 a1 = *(const f32x4*)(p + 4);
    u16x8 o;
    #pragma unroll
    for (int e = 0; e < 4; ++e) {
      o[e]     = f2bf_rne(a0[e]);
      o[e + 4] = f2bf_rne(a1[e]);
    }
    *(u16x8*)(Xb + g * 8) = o;
  }
}

// ---------------- main: bf16 GEMM, m97 structure ----------------
__global__ __launch_bounds__(256)
void w8a16_main_kernel(const unsigned short* __restrict__ Xb,  // [M][K] bf16
                       const unsigned short* __restrict__ Wb,  // [N][K] bf16
                       const float* __restrict__ S,            // [N]
                       const float* __restrict__ Bv,           // [N]
                       float*       __restrict__ O)            // [M][N]
{
  __shared__ unsigned short As[BM * BK];  // linear: global_load_lds dest
  __shared__ unsigned short Bs[BN * BK];

  const int tid  = threadIdx.x;
  const int lane = tid & 63;
  const int wid  = tid >> 6;       // 4 waves, 2x2
  const int wr   = wid >> 1;
  const int wc   = wid & 1;

  // XCD-chunked bijective swizzle: 5504 blocks = 8 XCDs x 688.
  const int p   = blockIdx.x;
  const int xcd = p & 7;
  const int seq = p >> 3;                 // 0..687
  const int bn_idx = seq >> 3;            // 0..85
  const int by_idx = xcd * 8 + (seq & 7); // 0..63
  const int row0 = by_idx * BM;
  const int col0 = bn_idx * BN;

  f32x4 acc[4][4] = {};

  // Staging: wave wid fills rows [wid*32, wid*32+32) of As and Bs, two 1KB
  // wave-loads each. LDS dest = wave-uniform base + lane*16 (HW rule);
  // per-lane global src: row += lane>>2, k += (lane&3)*8.
  const int a_base    = wid * 32;
  const int lane_row  = lane >> 2;
  const int lane_k    = (lane & 3) * 8;

  const int fr = lane & 15;
  const int fk = (lane >> 4) * 8;

  for (int kt = 0; kt < K_DIM; kt += BK) {
    __syncthreads();  // previous iteration's frag reads complete

    #pragma unroll
    for (int q = 0; q < 2; ++q) {
      const int rowblk = a_base + q * 16;
      const unsigned short* asrc = Xb + (long)(row0 + rowblk + lane_row) * K_DIM + kt + lane_k;
      const unsigned short* bsrc = Wb + (long)(col0 + rowblk + lane_row) * K_DIM + kt + lane_k;
      async_copy16(&As[rowblk * BK], asrc);
      async_copy16(&Bs[rowblk * BK], bsrc);
    }

    __syncthreads();  // drains vmcnt: tiles visible

    bf16x8 af[4], bfr[4];
    #pragma unroll
    for (int i = 0; i < 4; ++i)
      af[i] = *(const bf16x8*)&As[(wr * 64 + i * 16 + fr) * BK + fk];
    #pragma unroll
    for (int j = 0; j < 4; ++j)
      bfr[j] = *(const bf16x8*)&Bs[(wc * 64 + j * 16 + fr) * BK + fk];
    #pragma unroll
    for (int i = 0; i < 4; ++i)
      #pragma unroll
      for (int j = 0; j < 4; ++j)
        acc[i][j] = __builtin_amdgcn_mfma_f32_16x16x32_bf16(af[i], bfr[j], acc[i][j], 0, 0, 0);
  }

  // ---- epilogue: scale + bias in fp32, store f32 ----
  // C/D layout (verified m89): col = lane&15, row = (lane>>4)*4 + e
  const int erow = (lane >> 4) * 4;
  const int ecol = lane & 15;
  #pragma unroll
  for (int j = 0; j < 4; ++j) {
    const int col = col0 + wc * 64 + j * 16 + ecol;
    const float s  = S[col];
    const float bb = Bv[col];
    #pragma unroll
    for (int i = 0; i < 4; ++i) {
      const int rbase = row0 + wr * 64 + i * 16 + erow;
      #pragma unroll
      for (int e = 0; e < 4; ++e) {
        O[(long)(rbase + e) * N_DIM + col] = acc[i][j][e] * s + bb;
      }
    }
  }
}

// ---------------- fallback (round-3 kernel) if ws too small ----------------
#define PITCH 40
__global__ __launch_bounds__(256)
void w8a16_fallback_kernel(const float* __restrict__ X, const int* __restrict__ W,
                           const float* __restrict__ S, const float* __restrict__ Bv,
                           float* __restrict__ O)
{
  __shared__ unsigned short As[BM * PITCH];
  __shared__ unsigned short Bs[BN * PITCH];
  const int tid = threadIdx.x, lane = tid & 63, wid = tid >> 6;
  const int wr = wid >> 1, wc = wid & 1;
  const int p = blockIdx.x, xcd = p & 7, seq = p >> 3;
  const int bn_idx = seq >> 3, by_idx = xcd * 8 + (seq & 7);
  const int row0 = by_idx * BM, col0 = bn_idx * BN;
  f32x4 acc[4][4] = {};
  const int st_row = tid >> 1, st_kc = (tid & 1) * 16;
  const float* xsrc = X + (long)(row0 + st_row) * K_DIM + st_kc;
  const int*   wsrc = W + (long)(col0 + st_row) * K_DIM + st_kc;
  unsigned short* adst = &As[st_row * PITCH + st_kc];
  unsigned short* bdst = &Bs[st_row * PITCH + st_kc];
  const int fr = lane & 15, fk = (lane >> 4) * 8;
  for (int kt = 0; kt < K_DIM; kt += BK) {
    f32x4 a0 = *(const f32x4*)(xsrc + kt);
    f32x4 a1 = *(const f32x4*)(xsrc + kt + 4);
    f32x4 a2 = *(const f32x4*)(xsrc + kt + 8);
    f32x4 a3 = *(const f32x4*)(xsrc + kt + 12);
    i32x4 w0 = *(const i32x4*)(wsrc + kt);
    i32x4 w1 = *(const i32x4*)(wsrc + kt + 4);
    i32x4 w2 = *(const i32x4*)(wsrc + kt + 8);
    i32x4 w3 = *(const i32x4*)(wsrc + kt + 12);
    u16x8 pa0, pa1, pb0, pb1;
    #pragma unroll
    for (int e = 0; e < 4; ++e) {
      pa0[e] = f2bf_rne(a0[e]); pa0[e+4] = f2bf_rne(a1[e]);
      pa1[e] = f2bf_rne(a2[e]); pa1[e+4] = f2bf_rne(a3[e]);
      pb0[e] = i2bf(w0[e]);     pb0[e+4] = i2bf(w1[e]);
      pb1[e] = i2bf(w2[e]);     pb1[e+4] = i2bf(w3[e]);
    }
    __syncthreads();
    *(u16x8*)(adst) = pa0; *(u16x8*)(adst + 8) = pa1;
    *(u16x8*)(bdst) = pb0; *(u16x8*)(bdst + 8) = pb1;
    __syncthreads();
    bf16x8 af[4], bfr[4];
    #pragma unroll
    for (int i = 0; i < 4; ++i)
      af[i] = *(const bf16x8*)&As[(wr * 64 + i * 16 + fr) * PITCH + fk];
    #pragma unroll
    for (int j = 0; j < 4; ++j)
      bfr[j] = *(const bf16x8*)&Bs[(wc * 64 + j * 16 + fr) * PITCH + fk];
    #pragma unroll
    for (int i = 0; i < 4; ++i)
      #pragma unroll
      for (int j = 0; j < 4; ++j)
        acc[i][j] = __builtin_amdgcn_mfma_f32_16x16x32_bf16(af[i], bfr[j], acc[i][j], 0, 0, 0);
  }
  const int erow = (lane >> 4) * 4, ecol = lane & 15;
  #pragma unroll
  for (int j = 0; j < 4; ++j) {
    const int col = col0 + wc * 64 + j * 16 + ecol;
    const float s = S[col], bb = Bv[col];
    #pragma unroll
    for (int i = 0; i < 4; ++i) {
      const int rbase = row0 + wr * 64 + i * 16 + erow;
      #pragma unroll
      for (int e = 0; e < 4; ++e)
        O[(long)(rbase + e) * N_DIM + col] = acc[i][j][e] * s + bb;
    }
  }
}

extern "C" void kernel_launch(void* const* d_in, const int* in_sizes, int n_in,
                              void* d_out, int out_size, void* d_ws, size_t ws_size,
                              hipStream_t stream) {
  const float* x  = (const float*)d_in[0];
  const int*   w  = (const int*)d_in[1];
  const float* sc = (const float*)d_in[2];
  const float* bi = (const float*)d_in[3];
  float* out = (float*)d_out;

  const size_t w_elems = (size_t)N_DIM * K_DIM;   // 45,088,768
  const size_t x_elems = (size_t)M_DIM * K_DIM;   // 33,554,432
  const size_t need = (w_elems + x_elems) * sizeof(unsigned short);  // 157.3 MB

  const int grid = (M_DIM / BM) * (N_DIM / BN);  // 5504

  if (ws_size >= need) {
    unsigned short* Wb = (unsigned short*)d_ws;
    unsigned short* Xb = Wb + w_elems;
    dequant_w_kernel<<<2048, 256, 0, stream>>>(w, Wb);
    conv_x_kernel<<<2048, 256, 0, stream>>>(x, Xb);
    w8a16_main_kernel<<<grid, 256, 0, stream>>>(Xb, Wb, sc, bi, out);
  } else {
    w8a16_fallback_kernel<<<grid, 256, 0, stream>>>(x, w, sc, bi, out);
  }
}

// Round 6
// 969.748 us; speedup vs baseline: 1.5772x; 1.0214x over previous
//
#include <hip/hip_runtime.h>

// W8A16 GEMM: out[m,n] = scale[n] * sum_k x[m,k]*Wint[n,k] + bias[n]
// M=8192, N=11008, K=4096. Device dtypes: x f32, W int32, scales f32, bias f32, out f32.
// Round 6: round-5 8-phase 256x256 kernel + TAIL FIX (peeled last iteration with
// graded vmcnt drain 6/4/2/0 — vmcnt(6) was a no-op once prefetch stopped, racing
// the last K-tile's reads against in-flight global_load_lds).
#define M_DIM 8192
#define N_DIM 11008
#define K_DIM 4096
#define K_TILES 64   // K / 64

typedef __bf16 bf16x8 __attribute__((ext_vector_type(8)));
typedef float  f32x4  __attribute__((ext_vector_type(4)));
typedef int    i32x4  __attribute__((ext_vector_type(4)));
typedef unsigned short u16x8 __attribute__((ext_vector_type(8)));

__device__ __forceinline__ unsigned short f2bf_rne(float f) {
  unsigned u = __float_as_uint(f);
  u += 0x7fffu + ((u >> 16) & 1u);
  return (unsigned short)(u >> 16);
}
__device__ __forceinline__ unsigned short i2bf(int v) {
  float f = (float)v;  // |v| <= 127: exact in bf16
  return (unsigned short)(__float_as_uint(f) >> 16);
}
__device__ __forceinline__ void async_copy16(void* lds_dst, const void* g_src) {
  __builtin_amdgcn_global_load_lds(
      (const __attribute__((address_space(1))) void*)g_src,
      (__attribute__((address_space(3))) void*)lds_dst,
      16, 0, 0);
}

// ---------------- prepass: W int32 -> bf16 (exact) ----------------
__global__ __launch_bounds__(256)
void dequant_w_kernel(const int* __restrict__ W, unsigned short* __restrict__ Wb) {
  const int NG = N_DIM * K_DIM / 8;
  for (int g = blockIdx.x * 256 + threadIdx.x; g < NG; g += gridDim.x * 256) {
    const int* p = W + (size_t)g * 8;
    i32x4 w0 = *(const i32x4*)p;
    i32x4 w1 = *(const i32x4*)(p + 4);
    u16x8 o;
    #pragma unroll
    for (int e = 0; e < 4; ++e) { o[e] = i2bf(w0[e]); o[e + 4] = i2bf(w1[e]); }
    *(u16x8*)(Wb + (size_t)g * 8) = o;
  }
}

// ---------------- prepass: X f32 -> bf16 (RNE) ----------------
__global__ __launch_bounds__(256)
void conv_x_kernel(const float* __restrict__ X, unsigned short* __restrict__ Xb) {
  const int NG = M_DIM * K_DIM / 8;
  for (int g = blockIdx.x * 256 + threadIdx.x; g < NG; g += gridDim.x * 256) {
    const float* p = X + (size_t)g * 8;
    f32x4 a0 = *(const f32x4*)p;
    f32x4 a1 = *(const f32x4*)(p + 4);
    u16x8 o;
    #pragma unroll
    for (int e = 0; e < 4; ++e) { o[e] = f2bf_rne(a0[e]); o[e + 4] = f2bf_rne(a1[e]); }
    *(u16x8*)(Xb + (size_t)g * 8) = o;
  }
}

// ---------------- main: 256x256 8-phase bf16 GEMM ----------------
// LDS: buf b at b*32768 (A) / +16384 (B). Tile [256 rows][64 k] linear ushort,
// st_16x32 swizzle: col ^= 16 when (row & 4), applied as inverse-swizzled global
// source (global_load_lds dest stays linear) + swizzled ds_read (rule 21).
// Wave->frag interleave: M-frag i -> rows (2i+wr)*16; N-frag j -> rows (4j+wc)*16,
// so quadrant (MQ,NQ) reads exactly A-half MQ + B-half NQ.
// Retirement audit: unit staged at phase p is vmcnt-retired at p+3's wait; all
// steady-state stage->read gaps >= 5. Tail: peeled with drains 6/4/2/0.
__global__ __launch_bounds__(512, 2)
void w8a16_main_kernel(const unsigned short* __restrict__ Xb,  // [M][K] bf16
                       const unsigned short* __restrict__ Wb,  // [N][K] bf16
                       const float* __restrict__ S,
                       const float* __restrict__ Bv,
                       float*       __restrict__ O)
{
  __shared__ unsigned short sh[65536];  // 128 KB

  const int tid  = threadIdx.x;
  const int lane = tid & 63;
  const int wid  = tid >> 6;       // 8 waves
  const int wr   = wid >> 2;       // 0..1  (M)
  const int wc   = wid & 3;        // 0..3  (N)

  // T1: bijective XCD swizzle, 1376 = 8 x 172.
  const int swz = (blockIdx.x & 7) * 172 + (blockIdx.x >> 3);
  const int bm = swz / 43, bn = swz % 43;
  const int row0 = bm * 256, col0 = bn * 256;

  f32x4 acc[8][4] = {};

  // ---- fragment-read addressing (swizzle folded per-thread) ----
  const int fr  = lane & 15;
  const int fkk = (lane >> 4) * 8;          // {0,8,16,24}
  const int c0  = fkk ^ ((fr & 4) << 2);    // swizzled k-col base
  const int aoff = fr * 64 + c0;            // + (2i+wr)*1024 + 32*ks
  const int boff = fr * 64 + c0;            // + (4j+wc)*1024 + 32*ks (B base +16384)

  // ---- stage addressing: chunk = wid*2+q; within-half row = chunk*8 + lane/8 ----
  const int ch0 = wid * 2;
  const int sr0 = ch0 * 8 + (lane >> 3);                 // 0..127
  const int sr1 = sr0 + 8;
  const int sc0 = ((lane & 7) * 8) ^ ((sr0 & 4) << 2);   // inverse-swizzled src col
  const int sc1 = ((lane & 7) * 8) ^ ((sr1 & 4) << 2);
  const unsigned short* Xs0 = Xb + (size_t)(row0 + sr0) * K_DIM + sc0;
  const unsigned short* Xs1 = Xb + (size_t)(row0 + sr1) * K_DIM + sc1;
  const unsigned short* Ws0 = Wb + (size_t)(col0 + sr0) * K_DIM + sc0;
  const unsigned short* Ws1 = Wb + (size_t)(col0 + sr1) * K_DIM + sc1;
  const size_t HALF = (size_t)128 * K_DIM;

#define STAGE_X(st, h) do { \
    unsigned short* _d = sh + ((st) & 1) * 32768 + (h) * 8192 + ch0 * 512; \
    async_copy16(_d,       Xs0 + (size_t)(h) * HALF + (size_t)(st) * 64); \
    async_copy16(_d + 512, Xs1 + (size_t)(h) * HALF + (size_t)(st) * 64); \
  } while (0)
#define STAGE_W(st, h) do { \
    unsigned short* _d = sh + ((st) & 1) * 32768 + 16384 + (h) * 8192 + ch0 * 512; \
    async_copy16(_d,       Ws0 + (size_t)(h) * HALF + (size_t)(st) * 64); \
    async_copy16(_d + 512, Ws1 + (size_t)(h) * HALF + (size_t)(st) * 64); \
  } while (0)

#define PHASE(tt, MQ, NQ, STAGE_STMT, VMC) do { \
    const unsigned short* Ab = sh + ((tt) & 1) * 32768; \
    const unsigned short* Bb = Ab + 16384; \
    bf16x8 af[4][2], bfv[2][2]; \
    _Pragma("unroll") \
    for (int ii = 0; ii < 4; ++ii) { \
      af[ii][0] = *(const bf16x8*)&Ab[(2 * (4 * (MQ) + ii) + wr) * 1024 + aoff]; \
      af[ii][1] = *(const bf16x8*)&Ab[(2 * (4 * (MQ) + ii) + wr) * 1024 + aoff + 32]; \
    } \
    _Pragma("unroll") \
    for (int jj = 0; jj < 2; ++jj) { \
      bfv[jj][0] = *(const bf16x8*)&Bb[(4 * (2 * (NQ) + jj) + wc) * 1024 + boff]; \
      bfv[jj][1] = *(const bf16x8*)&Bb[(4 * (2 * (NQ) + jj) + wc) * 1024 + boff + 32]; \
    } \
    STAGE_STMT; \
    asm volatile("s_waitcnt vmcnt(" #VMC ")" ::: "memory"); \
    __builtin_amdgcn_s_barrier(); \
    __builtin_amdgcn_s_setprio(1); \
    _Pragma("unroll") \
    for (int ii = 0; ii < 4; ++ii) \
      _Pragma("unroll") \
      for (int jj = 0; jj < 2; ++jj) { \
        acc[4*(MQ)+ii][2*(NQ)+jj] = __builtin_amdgcn_mfma_f32_16x16x32_bf16(af[ii][0], bfv[jj][0], acc[4*(MQ)+ii][2*(NQ)+jj], 0, 0, 0); \
        acc[4*(MQ)+ii][2*(NQ)+jj] = __builtin_amdgcn_mfma_f32_16x16x32_bf16(af[ii][1], bfv[jj][1], acc[4*(MQ)+ii][2*(NQ)+jj], 0, 0, 0); \
      } \
    __builtin_amdgcn_s_setprio(0); \
    __builtin_amdgcn_s_barrier(); \
    __builtin_amdgcn_sched_barrier(0); \
  } while (0)

  // ---- prologue: tile 0 full + A-lo(1), B-lo(1) issued; vmcnt(6) lands tile-0's
  //      first 3 units; X(0,1) (insts 7,8) lands at P1's wait, first read P3. ----
  STAGE_X(0, 0); STAGE_W(0, 0); STAGE_W(0, 1); STAGE_X(0, 1);
  STAGE_X(1, 0); STAGE_W(1, 0);
  asm volatile("s_waitcnt vmcnt(6)" ::: "memory");
  __builtin_amdgcn_s_barrier();

  // ---- main loop: iterations 0..K_TILES/2-2, always prefetching ----
  for (int i = 0; i < K_TILES / 2 - 1; ++i) {
    const int u = 2 * i, v = 2 * i + 1;
    PHASE(u, 0, 0, { STAGE_W(v, 1); },     6);
    PHASE(u, 0, 1, { STAGE_X(v, 1); },     6);
    PHASE(u, 1, 0, { STAGE_X(u + 2, 0); }, 6);
    PHASE(u, 1, 1, { STAGE_W(u + 2, 0); }, 6);
    PHASE(v, 0, 0, { STAGE_W(u + 2, 1); }, 6);
    PHASE(v, 0, 1, { STAGE_X(u + 2, 1); }, 6);
    PHASE(v, 1, 0, { STAGE_X(v + 2, 0); }, 6);
    PHASE(v, 1, 1, { STAGE_W(v + 2, 0); }, 6);
  }

  // ---- peeled last iteration (u=62, v=63): graded drain so every remaining
  //      unit is retired >=1 phase before its read (P2 retires X(63,0)+W(63,0)
  //      for P5; P3 retires W(63,1) for P6; P4 retires X(63,1) for P7). ----
  {
    const int u = K_TILES - 2, v = K_TILES - 1;
    PHASE(u, 0, 0, { STAGE_W(v, 1); }, 6);
    PHASE(u, 0, 1, { STAGE_X(v, 1); }, 4);
    PHASE(u, 1, 0, {},                 2);
    PHASE(u, 1, 1, {},                 0);
    PHASE(v, 0, 0, {},                 0);
    PHASE(v, 0, 1, {},                 0);
    PHASE(v, 1, 0, {},                 0);
    PHASE(v, 1, 1, {},                 0);
  }

  // ---- epilogue: scale + bias, store f32 ----
  // C/D layout (m89): col = lane&15, row = (lane>>4)*4 + e
  const int erow = (lane >> 4) * 4;
  const int ecol = lane & 15;
  #pragma unroll
  for (int j = 0; j < 4; ++j) {
    const int ocol = col0 + (4 * j + wc) * 16 + ecol;
    const float s  = S[ocol];
    const float bb = Bv[ocol];
    #pragma unroll
    for (int ii = 0; ii < 8; ++ii) {
      const int orow = row0 + (2 * ii + wr) * 16 + erow;
      #pragma unroll
      for (int e = 0; e < 4; ++e)
        O[(size_t)(orow + e) * N_DIM + ocol] = acc[ii][j][e] * s + bb;
    }
  }
#undef PHASE
#undef STAGE_X
#undef STAGE_W
}

// ---------------- fallback (round-3 kernel, verified) ----------------
#define FB_BM 128
#define FB_BK 32
#define PITCH 40
__global__ __launch_bounds__(256)
void w8a16_fallback_kernel(const float* __restrict__ X, const int* __restrict__ W,
                           const float* __restrict__ S, const float* __restrict__ Bv,
                           float* __restrict__ O)
{
  __shared__ unsigned short As[FB_BM * PITCH];
  __shared__ unsigned short Bs[FB_BM * PITCH];
  const int tid = threadIdx.x, lane = tid & 63, wid = tid >> 6;
  const int wr = wid >> 1, wc = wid & 1;
  const int p = blockIdx.x, xcd = p & 7, seq = p >> 3;
  const int bn_idx = seq >> 3, by_idx = xcd * 8 + (seq & 7);
  const int row0 = by_idx * FB_BM, col0 = bn_idx * FB_BM;
  f32x4 acc[4][4] = {};
  const int st_row = tid >> 1, st_kc = (tid & 1) * 16;
  const float* xsrc = X + (size_t)(row0 + st_row) * K_DIM + st_kc;
  const int*   wsrc = W + (size_t)(col0 + st_row) * K_DIM + st_kc;
  unsigned short* adst = &As[st_row * PITCH + st_kc];
  unsigned short* bdst = &Bs[st_row * PITCH + st_kc];
  const int fr = lane & 15, fk = (lane >> 4) * 8;
  for (int kt = 0; kt < K_DIM; kt += FB_BK) {
    f32x4 a0 = *(const f32x4*)(xsrc + kt);
    f32x4 a1 = *(const f32x4*)(xsrc + kt + 4);
    f32x4 a2 = *(const f32x4*)(xsrc + kt + 8);
    f32x4 a3 = *(const f32x4*)(xsrc + kt + 12);
    i32x4 w0 = *(const i32x4*)(wsrc + kt);
    i32x4 w1 = *(const i32x4*)(wsrc + kt + 4);
    i32x4 w2 = *(const i32x4*)(wsrc + kt + 8);
    i32x4 w3 = *(const i32x4*)(wsrc + kt + 12);
    u16x8 pa0, pa1, pb0, pb1;
    #pragma unroll
    for (int e = 0; e < 4; ++e) {
      pa0[e] = f2bf_rne(a0[e]); pa0[e+4] = f2bf_rne(a1[e]);
      pa1[e] = f2bf_rne(a2[e]); pa1[e+4] = f2bf_rne(a3[e]);
      pb0[e] = i2bf(w0[e]);     pb0[e+4] = i2bf(w1[e]);
      pb1[e] = i2bf(w2[e]);     pb1[e+4] = i2bf(w3[e]);
    }
    __syncthreads();
    *(u16x8*)(adst) = pa0; *(u16x8*)(adst + 8) = pa1;
    *(u16x8*)(bdst) = pb0; *(u16x8*)(bdst + 8) = pb1;
    __syncthreads();
    bf16x8 af[4], bfr[4];
    #pragma unroll
    for (int i = 0; i < 4; ++i)
      af[i] = *(const bf16x8*)&As[(wr * 64 + i * 16 + fr) * PITCH + fk];
    #pragma unroll
    for (int j = 0; j < 4; ++j)
      bfr[j] = *(const bf16x8*)&Bs[(wc * 64 + j * 16 + fr) * PITCH + fk];
    #pragma unroll
    for (int i = 0; i < 4; ++i)
      #pragma unroll
      for (int j = 0; j < 4; ++j)
        acc[i][j] = __builtin_amdgcn_mfma_f32_16x16x32_bf16(af[i], bfr[j], acc[i][j], 0, 0, 0);
  }
  const int erow = (lane >> 4) * 4, ecol = lane & 15;
  #pragma unroll
  for (int j = 0; j < 4; ++j) {
    const int col = col0 + wc * 64 + j * 16 + ecol;
    const float s = S[col], bb = Bv[col];
    #pragma unroll
    for (int i = 0; i < 4; ++i) {
      const int rbase = row0 + wr * 64 + i * 16 + erow;
      #pragma unroll
      for (int e = 0; e < 4; ++e)
        O[(size_t)(rbase + e) * N_DIM + col] = acc[i][j][e] * s + bb;
    }
  }
}

extern "C" void kernel_launch(void* const* d_in, const int* in_sizes, int n_in,
                              void* d_out, int out_size, void* d_ws, size_t ws_size,
                              hipStream_t stream) {
  const float* x  = (const float*)d_in[0];
  const int*   w  = (const int*)d_in[1];
  const float* sc = (const float*)d_in[2];
  const float* bi = (const float*)d_in[3];
  float* out = (float*)d_out;

  const size_t w_elems = (size_t)N_DIM * K_DIM;
  const size_t x_elems = (size_t)M_DIM * K_DIM;
  const size_t need = (w_elems + x_elems) * sizeof(unsigned short);

  if (ws_size >= need) {
    unsigned short* Wb = (unsigned short*)d_ws;
    unsigned short* Xb = Wb + w_elems;
    dequant_w_kernel<<<2048, 256, 0, stream>>>(w, Wb);
    conv_x_kernel<<<2048, 256, 0, stream>>>(x, Xb);
    const int grid = (M_DIM / 256) * (N_DIM / 256);  // 32 * 43 = 1376
    w8a16_main_kernel<<<grid, 512, 0, stream>>>(Xb, Wb, sc, bi, out);
  } else {
    const int grid = (M_DIM / FB_BM) * (N_DIM / FB_BM);
    w8a16_fallback_kernel<<<grid, 256, 0, stream>>>(x, w, sc, bi, out);
  }
}

// Round 7
// 802.633 us; speedup vs baseline: 1.9056x; 1.2082x over previous
//
#include <hip/hip_runtime.h>

// W8A16 GEMM: out[m,n] = scale[n] * sum_k x[m,k]*Wint[n,k] + bias[n]
// M=8192, N=11008, K=4096. Device dtypes: x f32, W int32, scales f32, bias f32, out f32.
// Round 7: full-strength T2 swizzle. Round-6's 1-bit XOR ((row&4)<<2) left 8-way
// bank conflicts (SQ_LDS_BANK_CONFLICT=1.35e8, MfmaUtil stuck at 33%). Now
// col ^= (row&7)<<3 (ushorts) = G4's (row&7)<<4 bytes: 8 slots x 4 banks = all 32.
// NOTE: sw covers ushort-bit 5, so each k-slot address must XOR separately
// ((kc ^ sw), not (kc0^sw)+32 — carry would escape the row).
#define M_DIM 8192
#define N_DIM 11008
#define K_DIM 4096
#define K_TILES 64   // K / 64

typedef __bf16 bf16x8 __attribute__((ext_vector_type(8)));
typedef float  f32x4  __attribute__((ext_vector_type(4)));
typedef int    i32x4  __attribute__((ext_vector_type(4)));
typedef unsigned short u16x8 __attribute__((ext_vector_type(8)));

__device__ __forceinline__ unsigned short f2bf_rne(float f) {
  unsigned u = __float_as_uint(f);
  u += 0x7fffu + ((u >> 16) & 1u);
  return (unsigned short)(u >> 16);
}
__device__ __forceinline__ unsigned short i2bf(int v) {
  float f = (float)v;  // |v| <= 127: exact in bf16
  return (unsigned short)(__float_as_uint(f) >> 16);
}
__device__ __forceinline__ void async_copy16(void* lds_dst, const void* g_src) {
  __builtin_amdgcn_global_load_lds(
      (const __attribute__((address_space(1))) void*)g_src,
      (__attribute__((address_space(3))) void*)lds_dst,
      16, 0, 0);
}

// ---------------- prepass: W int32 -> bf16 (exact) ----------------
__global__ __launch_bounds__(256)
void dequant_w_kernel(const int* __restrict__ W, unsigned short* __restrict__ Wb) {
  const int NG = N_DIM * K_DIM / 8;
  for (int g = blockIdx.x * 256 + threadIdx.x; g < NG; g += gridDim.x * 256) {
    const int* p = W + (size_t)g * 8;
    i32x4 w0 = *(const i32x4*)p;
    i32x4 w1 = *(const i32x4*)(p + 4);
    u16x8 o;
    #pragma unroll
    for (int e = 0; e < 4; ++e) { o[e] = i2bf(w0[e]); o[e + 4] = i2bf(w1[e]); }
    *(u16x8*)(Wb + (size_t)g * 8) = o;
  }
}

// ---------------- prepass: X f32 -> bf16 (RNE) ----------------
__global__ __launch_bounds__(256)
void conv_x_kernel(const float* __restrict__ X, unsigned short* __restrict__ Xb) {
  const int NG = M_DIM * K_DIM / 8;
  for (int g = blockIdx.x * 256 + threadIdx.x; g < NG; g += gridDim.x * 256) {
    const float* p = X + (size_t)g * 8;
    f32x4 a0 = *(const f32x4*)p;
    f32x4 a1 = *(const f32x4*)(p + 4);
    u16x8 o;
    #pragma unroll
    for (int e = 0; e < 4; ++e) { o[e] = f2bf_rne(a0[e]); o[e + 4] = f2bf_rne(a1[e]); }
    *(u16x8*)(Xb + (size_t)g * 8) = o;
  }
}

// ---------------- main: 256x256 8-phase bf16 GEMM ----------------
// LDS: buf b at b*32768 (A) / +16384 (B). Tile [256 rows][64 k] ushort,
// swizzle LDS[row][col ^ ((row&7)<<3)] = global[row][col], realized as
// inverse-swizzled global source (global_load_lds dest linear) + swizzled ds_read.
// Wave->frag interleave: M-frag i -> rows (2i+wr)*16; N-frag j -> rows (4j+wc)*16,
// so quadrant (MQ,NQ) reads exactly A-half MQ + B-half NQ.
// Retirement audit: unit staged at phase p is vmcnt-retired at p+3's wait; all
// steady-state stage->read gaps >= 5. Tail: peeled with drains 6/4/2/0.
__global__ __launch_bounds__(512, 2)
void w8a16_main_kernel(const unsigned short* __restrict__ Xb,  // [M][K] bf16
                       const unsigned short* __restrict__ Wb,  // [N][K] bf16
                       const float* __restrict__ S,
                       const float* __restrict__ Bv,
                       float*       __restrict__ O)
{
  __shared__ unsigned short sh[65536];  // 128 KB

  const int tid  = threadIdx.x;
  const int lane = tid & 63;
  const int wid  = tid >> 6;       // 8 waves
  const int wr   = wid >> 2;       // 0..1  (M)
  const int wc   = wid & 3;        // 0..3  (N)

  // T1: bijective XCD swizzle, 1376 = 8 x 172.
  const int swz = (blockIdx.x & 7) * 172 + (blockIdx.x >> 3);
  const int bm = swz / 43, bn = swz % 43;
  const int row0 = bm * 256, col0 = bn * 256;

  f32x4 acc[8][4] = {};

  // ---- fragment-read addressing (3-bit swizzle; per-k-slot XOR) ----
  const int fr   = lane & 15;
  const int fkk  = (lane >> 4) * 8;            // {0,8,16,24}
  const int sw_r = (fr & 7) << 3;              // swizzle (ushorts)
  const int aoff0 = fr * 64 + (fkk ^ sw_r);          // k-slot 0
  const int aoff1 = fr * 64 + ((fkk + 32) ^ sw_r);   // k-slot 1

  // ---- stage addressing: chunk = wid*2+q; within-half row = chunk*8 + lane/8 ----
  const int ch0 = wid * 2;
  const int sr0 = ch0 * 8 + (lane >> 3);                 // 0..127
  const int sr1 = sr0 + 8;                               // (sr1&7)==(sr0&7)
  const int sc0 = ((lane & 7) * 8) ^ ((sr0 & 7) << 3);   // inverse-swizzled src col
  const int sc1 = ((lane & 7) * 8) ^ ((sr1 & 7) << 3);
  const unsigned short* Xs0 = Xb + (size_t)(row0 + sr0) * K_DIM + sc0;
  const unsigned short* Xs1 = Xb + (size_t)(row0 + sr1) * K_DIM + sc1;
  const unsigned short* Ws0 = Wb + (size_t)(col0 + sr0) * K_DIM + sc0;
  const unsigned short* Ws1 = Wb + (size_t)(col0 + sr1) * K_DIM + sc1;
  const size_t HALF = (size_t)128 * K_DIM;

#define STAGE_X(st, h) do { \
    unsigned short* _d = sh + ((st) & 1) * 32768 + (h) * 8192 + ch0 * 512; \
    async_copy16(_d,       Xs0 + (size_t)(h) * HALF + (size_t)(st) * 64); \
    async_copy16(_d + 512, Xs1 + (size_t)(h) * HALF + (size_t)(st) * 64); \
  } while (0)
#define STAGE_W(st, h) do { \
    unsigned short* _d = sh + ((st) & 1) * 32768 + 16384 + (h) * 8192 + ch0 * 512; \
    async_copy16(_d,       Ws0 + (size_t)(h) * HALF + (size_t)(st) * 64); \
    async_copy16(_d + 512, Ws1 + (size_t)(h) * HALF + (size_t)(st) * 64); \
  } while (0)

#define PHASE(tt, MQ, NQ, STAGE_STMT, VMC) do { \
    const unsigned short* Ab = sh + ((tt) & 1) * 32768; \
    const unsigned short* Bb = Ab + 16384; \
    bf16x8 af[4][2], bfv[2][2]; \
    _Pragma("unroll") \
    for (int ii = 0; ii < 4; ++ii) { \
      af[ii][0] = *(const bf16x8*)&Ab[(2 * (4 * (MQ) + ii) + wr) * 1024 + aoff0]; \
      af[ii][1] = *(const bf16x8*)&Ab[(2 * (4 * (MQ) + ii) + wr) * 1024 + aoff1]; \
    } \
    _Pragma("unroll") \
    for (int jj = 0; jj < 2; ++jj) { \
      bfv[jj][0] = *(const bf16x8*)&Bb[(4 * (2 * (NQ) + jj) + wc) * 1024 + boff0]; \
      bfv[jj][1] = *(const bf16x8*)&Bb[(4 * (2 * (NQ) + jj) + wc) * 1024 + boff1]; \
    } \
    STAGE_STMT; \
    asm volatile("s_waitcnt vmcnt(" #VMC ")" ::: "memory"); \
    __builtin_amdgcn_s_barrier(); \
    __builtin_amdgcn_s_setprio(1); \
    _Pragma("unroll") \
    for (int ii = 0; ii < 4; ++ii) \
      _Pragma("unroll") \
      for (int jj = 0; jj < 2; ++jj) { \
        acc[4*(MQ)+ii][2*(NQ)+jj] = __builtin_amdgcn_mfma_f32_16x16x32_bf16(af[ii][0], bfv[jj][0], acc[4*(MQ)+ii][2*(NQ)+jj], 0, 0, 0); \
        acc[4*(MQ)+ii][2*(NQ)+jj] = __builtin_amdgcn_mfma_f32_16x16x32_bf16(af[ii][1], bfv[jj][1], acc[4*(MQ)+ii][2*(NQ)+jj], 0, 0, 0); \
      } \
    __builtin_amdgcn_s_setprio(0); \
    __builtin_amdgcn_s_barrier(); \
    __builtin_amdgcn_sched_barrier(0); \
  } while (0)

  const int boff0 = aoff0;  // identical per-lane formula; B tile base differs
  const int boff1 = aoff1;

  // ---- prologue: tile 0 full + A-lo(1), B-lo(1) issued ----
  STAGE_X(0, 0); STAGE_W(0, 0); STAGE_W(0, 1); STAGE_X(0, 1);
  STAGE_X(1, 0); STAGE_W(1, 0);
  asm volatile("s_waitcnt vmcnt(6)" ::: "memory");
  __builtin_amdgcn_s_barrier();

  // ---- main loop: iterations 0..K_TILES/2-2, always prefetching ----
  for (int i = 0; i < K_TILES / 2 - 1; ++i) {
    const int u = 2 * i, v = 2 * i + 1;
    PHASE(u, 0, 0, { STAGE_W(v, 1); },     6);
    PHASE(u, 0, 1, { STAGE_X(v, 1); },     6);
    PHASE(u, 1, 0, { STAGE_X(u + 2, 0); }, 6);
    PHASE(u, 1, 1, { STAGE_W(u + 2, 0); }, 6);
    PHASE(v, 0, 0, { STAGE_W(u + 2, 1); }, 6);
    PHASE(v, 0, 1, { STAGE_X(u + 2, 1); }, 6);
    PHASE(v, 1, 0, { STAGE_X(v + 2, 0); }, 6);
    PHASE(v, 1, 1, { STAGE_W(v + 2, 0); }, 6);
  }

  // ---- peeled last iteration (u=62, v=63): graded drain 6/4/2/0 ----
  {
    const int u = K_TILES - 2, v = K_TILES - 1;
    PHASE(u, 0, 0, { STAGE_W(v, 1); }, 6);
    PHASE(u, 0, 1, { STAGE_X(v, 1); }, 4);
    PHASE(u, 1, 0, {},                 2);
    PHASE(u, 1, 1, {},                 0);
    PHASE(v, 0, 0, {},                 0);
    PHASE(v, 0, 1, {},                 0);
    PHASE(v, 1, 0, {},                 0);
    PHASE(v, 1, 1, {},                 0);
  }

  // ---- epilogue: scale + bias, store f32 ----
  // C/D layout (m89): col = lane&15, row = (lane>>4)*4 + e
  const int erow = (lane >> 4) * 4;
  const int ecol = lane & 15;
  #pragma unroll
  for (int j = 0; j < 4; ++j) {
    const int ocol = col0 + (4 * j + wc) * 16 + ecol;
    const float s  = S[ocol];
    const float bb = Bv[ocol];
    #pragma unroll
    for (int ii = 0; ii < 8; ++ii) {
      const int orow = row0 + (2 * ii + wr) * 16 + erow;
      #pragma unroll
      for (int e = 0; e < 4; ++e)
        O[(size_t)(orow + e) * N_DIM + ocol] = acc[ii][j][e] * s + bb;
    }
  }
#undef PHASE
#undef STAGE_X
#undef STAGE_W
}

// ---------------- fallback (round-3 kernel, verified) ----------------
#define FB_BM 128
#define FB_BK 32
#define PITCH 40
__global__ __launch_bounds__(256)
void w8a16_fallback_kernel(const float* __restrict__ X, const int* __restrict__ W,
                           const float* __restrict__ S, const float* __restrict__ Bv,
                           float* __restrict__ O)
{
  __shared__ unsigned short As[FB_BM * PITCH];
  __shared__ unsigned short Bs[FB_BM * PITCH];
  const int tid = threadIdx.x, lane = tid & 63, wid = tid >> 6;
  const int wr = wid >> 1, wc = wid & 1;
  const int p = blockIdx.x, xcd = p & 7, seq = p >> 3;
  const int bn_idx = seq >> 3, by_idx = xcd * 8 + (seq & 7);
  const int row0 = by_idx * FB_BM, col0 = bn_idx * FB_BM;
  f32x4 acc[4][4] = {};
  const int st_row = tid >> 1, st_kc = (tid & 1) * 16;
  const float* xsrc = X + (size_t)(row0 + st_row) * K_DIM + st_kc;
  const int*   wsrc = W + (size_t)(col0 + st_row) * K_DIM + st_kc;
  unsigned short* adst = &As[st_row * PITCH + st_kc];
  unsigned short* bdst = &Bs[st_row * PITCH + st_kc];
  const int fr = lane & 15, fk = (lane >> 4) * 8;
  for (int kt = 0; kt < K_DIM; kt += FB_BK) {
    f32x4 a0 = *(const f32x4*)(xsrc + kt);
    f32x4 a1 = *(const f32x4*)(xsrc + kt + 4);
    f32x4 a2 = *(const f32x4*)(xsrc + kt + 8);
    f32x4 a3 = *(const f32x4*)(xsrc + kt + 12);
    i32x4 w0 = *(const i32x4*)(wsrc + kt);
    i32x4 w1 = *(const i32x4*)(wsrc + kt + 4);
    i32x4 w2 = *(const i32x4*)(wsrc + kt + 8);
    i32x4 w3 = *(const i32x4*)(wsrc + kt + 12);
    u16x8 pa0, pa1, pb0, pb1;
    #pragma unroll
    for (int e = 0; e < 4; ++e) {
      pa0[e] = f2bf_rne(a0[e]); pa0[e+4] = f2bf_rne(a1[e]);
      pa1[e] = f2bf_rne(a2[e]); pa1[e+4] = f2bf_rne(a3[e]);
      pb0[e] = i2bf(w0[e]);     pb0[e+4] = i2bf(w1[e]);
      pb1[e] = i2bf(w2[e]);     pb1[e+4] = i2bf(w3[e]);
    }
    __syncthreads();
    *(u16x8*)(adst) = pa0; *(u16x8*)(adst + 8) = pa1;
    *(u16x8*)(bdst) = pb0; *(u16x8*)(bdst + 8) = pb1;
    __syncthreads();
    bf16x8 af[4], bfr[4];
    #pragma unroll
    for (int i = 0; i < 4; ++i)
      af[i] = *(const bf16x8*)&As[(wr * 64 + i * 16 + fr) * PITCH + fk];
    #pragma unroll
    for (int j = 0; j < 4; ++j)
      bfr[j] = *(const bf16x8*)&Bs[(wc * 64 + j * 16 + fr) * PITCH + fk];
    #pragma unroll
    for (int i = 0; i < 4; ++i)
      #pragma unroll
      for (int j = 0; j < 4; ++j)
        acc[i][j] = __builtin_amdgcn_mfma_f32_16x16x32_bf16(af[i], bfr[j], acc[i][j], 0, 0, 0);
  }
  const int erow = (lane >> 4) * 4, ecol = lane & 15;
  #pragma unroll
  for (int j = 0; j < 4; ++j) {
    const int col = col0 + wc * 64 + j * 16 + ecol;
    const float s = S[col], bb = Bv[col];
    #pragma unroll
    for (int i = 0; i < 4; ++i) {
      const int rbase = row0 + wr * 64 + i * 16 + erow;
      #pragma unroll
      for (int e = 0; e < 4; ++e)
        O[(size_t)(rbase + e) * N_DIM + col] = acc[i][j][e] * s + bb;
    }
  }
}

extern "C" void kernel_launch(void* const* d_in, const int* in_sizes, int n_in,
                              void* d_out, int out_size, void* d_ws, size_t ws_size,
                              hipStream_t stream) {
  const float* x  = (const float*)d_in[0];
  const int*   w  = (const int*)d_in[1];
  const float* sc = (const float*)d_in[2];
  const float* bi = (const float*)d_in[3];
  float* out = (float*)d_out;

  const size_t w_elems = (size_t)N_DIM * K_DIM;
  const size_t x_elems = (size_t)M_DIM * K_DIM;
  const size_t need = (w_elems + x_elems) * sizeof(unsigned short);

  if (ws_size >= need) {
    unsigned short* Wb = (unsigned short*)d_ws;
    unsigned short* Xb = Wb + w_elems;
    dequant_w_kernel<<<2048, 256, 0, stream>>>(w, Wb);
    conv_x_kernel<<<2048, 256, 0, stream>>>(x, Xb);
    const int grid = (M_DIM / 256) * (N_DIM / 256);  // 32 * 43 = 1376
    w8a16_main_kernel<<<grid, 512, 0, stream>>>(Xb, Wb, sc, bi, out);
  } else {
    const int grid = (M_DIM / FB_BM) * (N_DIM / FB_BM);
    w8a16_fallback_kernel<<<grid, 256, 0, stream>>>(x, w, sc, bi, out);
  }
}

// Round 8
// 717.482 us; speedup vs baseline: 2.1318x; 1.1187x over previous
//
#include <hip/hip_runtime.h>

// W8A16 GEMM: out[m,n] = scale[n] * sum_k x[m,k]*Wint[n,k] + bias[n]
// M=8192, N=11008, K=4096. Device dtypes: x f32, W int32, scales f32, bias f32, out f32.
// Round 8: snake quadrant order (00->01->11->10) with operand reuse in regs
// (ds_read 48 -> 24 per K-tile per wave) + vmcnt 6 -> 8 (max 2-buffer prefetch
// depth; RAW: retire at stage+4, read at stage+5; WAR: >=1 barrier, re-audited).
#define M_DIM 8192
#define N_DIM 11008
#define K_DIM 4096
#define K_TILES 64   // K / 64

typedef __bf16 bf16x8 __attribute__((ext_vector_type(8)));
typedef float  f32x4  __attribute__((ext_vector_type(4)));
typedef int    i32x4  __attribute__((ext_vector_type(4)));
typedef unsigned short u16x8 __attribute__((ext_vector_type(8)));

__device__ __forceinline__ unsigned short f2bf_rne(float f) {
  unsigned u = __float_as_uint(f);
  u += 0x7fffu + ((u >> 16) & 1u);
  return (unsigned short)(u >> 16);
}
__device__ __forceinline__ unsigned short i2bf(int v) {
  float f = (float)v;  // |v| <= 127: exact in bf16
  return (unsigned short)(__float_as_uint(f) >> 16);
}
__device__ __forceinline__ void async_copy16(void* lds_dst, const void* g_src) {
  __builtin_amdgcn_global_load_lds(
      (const __attribute__((address_space(1))) void*)g_src,
      (__attribute__((address_space(3))) void*)lds_dst,
      16, 0, 0);
}

// ---------------- prepass: W int32 -> bf16 (exact) ----------------
__global__ __launch_bounds__(256)
void dequant_w_kernel(const int* __restrict__ W, unsigned short* __restrict__ Wb) {
  const int NG = N_DIM * K_DIM / 8;
  for (int g = blockIdx.x * 256 + threadIdx.x; g < NG; g += gridDim.x * 256) {
    const int* p = W + (size_t)g * 8;
    i32x4 w0 = *(const i32x4*)p;
    i32x4 w1 = *(const i32x4*)(p + 4);
    u16x8 o;
    #pragma unroll
    for (int e = 0; e < 4; ++e) { o[e] = i2bf(w0[e]); o[e + 4] = i2bf(w1[e]); }
    *(u16x8*)(Wb + (size_t)g * 8) = o;
  }
}

// ---------------- prepass: X f32 -> bf16 (RNE) ----------------
__global__ __launch_bounds__(256)
void conv_x_kernel(const float* __restrict__ X, unsigned short* __restrict__ Xb) {
  const int NG = M_DIM * K_DIM / 8;
  for (int g = blockIdx.x * 256 + threadIdx.x; g < NG; g += gridDim.x * 256) {
    const float* p = X + (size_t)g * 8;
    f32x4 a0 = *(const f32x4*)p;
    f32x4 a1 = *(const f32x4*)(p + 4);
    u16x8 o;
    #pragma unroll
    for (int e = 0; e < 4; ++e) { o[e] = f2bf_rne(a0[e]); o[e + 4] = f2bf_rne(a1[e]); }
    *(u16x8*)(Xb + (size_t)g * 8) = o;
  }
}

// ---------------- main: 256x256 8-phase bf16 GEMM ----------------
// LDS: buf b at b*32768 (A) / +16384 (B). Tile [256 rows][64 k] ushort,
// swizzle LDS[row][col ^ ((row&7)<<3)] = global[row][col] (inverse-swizzled
// global source, linear global_load_lds dest, swizzled ds_read).
// Snake order per tile: (MQ,NQ) = (0,0)->(0,1)->(1,1)->(1,0); A-frags reused
// across NQ-switch, B-frags (both halves in regs) across MQ-switch.
// RAW audit (vmcnt(8), 1 stage-unit/phase): unit staged at phase p retires at
// p+4's wait; first read at p+5 (or p+6), behind p+4's end barrier. Tail peeled
// with grades 8,8,8,4,2,0,0,0 (traced: every unit retired >=1 phase + barrier
// before its read).
__global__ __launch_bounds__(512, 2)
void w8a16_main_kernel(const unsigned short* __restrict__ Xb,  // [M][K] bf16
                       const unsigned short* __restrict__ Wb,  // [N][K] bf16
                       const float* __restrict__ S,
                       const float* __restrict__ Bv,
                       float*       __restrict__ O)
{
  __shared__ unsigned short sh[65536];  // 128 KB

  const int tid  = threadIdx.x;
  const int lane = tid & 63;
  const int wid  = tid >> 6;       // 8 waves
  const int wr   = wid >> 2;       // 0..1  (M)
  const int wc   = wid & 3;        // 0..3  (N)

  // T1: bijective XCD swizzle, 1376 = 8 x 172.
  const int swz = (blockIdx.x & 7) * 172 + (blockIdx.x >> 3);
  const int bm = swz / 43, bn = swz % 43;
  const int row0 = bm * 256, col0 = bn * 256;

  f32x4 acc[8][4] = {};

  // Persistent fragment registers (reused across phases)
  bf16x8 af[4][2];      // A-half fragments for current MQ [ii][kslice]
  bf16x8 bq[2][2][2];   // B fragments [NQ][jj][kslice], both halves live

  // ---- fragment-read addressing (3-bit swizzle; per-k-slot XOR) ----
  const int fr   = lane & 15;
  const int fkk  = (lane >> 4) * 8;            // {0,8,16,24}
  const int sw_r = (fr & 7) << 3;              // swizzle (ushorts)
  const int aoff0 = fr * 64 + (fkk ^ sw_r);          // k-slot 0
  const int aoff1 = fr * 64 + ((fkk + 32) ^ sw_r);   // k-slot 1
  const int boff0 = aoff0;
  const int boff1 = aoff1;

  // ---- stage addressing: chunk = wid*2+q; within-half row = chunk*8 + lane/8 ----
  const int ch0 = wid * 2;
  const int sr0 = ch0 * 8 + (lane >> 3);                 // 0..127
  const int sr1 = sr0 + 8;                               // (sr1&7)==(sr0&7)
  const int sc0 = ((lane & 7) * 8) ^ ((sr0 & 7) << 3);   // inverse-swizzled src col
  const int sc1 = ((lane & 7) * 8) ^ ((sr1 & 7) << 3);
  const unsigned short* Xs0 = Xb + (size_t)(row0 + sr0) * K_DIM + sc0;
  const unsigned short* Xs1 = Xb + (size_t)(row0 + sr1) * K_DIM + sc1;
  const unsigned short* Ws0 = Wb + (size_t)(col0 + sr0) * K_DIM + sc0;
  const unsigned short* Ws1 = Wb + (size_t)(col0 + sr1) * K_DIM + sc1;
  const size_t HALF = (size_t)128 * K_DIM;

#define STAGE_X(st, h) do { \
    unsigned short* _d = sh + ((st) & 1) * 32768 + (h) * 8192 + ch0 * 512; \
    async_copy16(_d,       Xs0 + (size_t)(h) * HALF + (size_t)(st) * 64); \
    async_copy16(_d + 512, Xs1 + (size_t)(h) * HALF + (size_t)(st) * 64); \
  } while (0)
#define STAGE_W(st, h) do { \
    unsigned short* _d = sh + ((st) & 1) * 32768 + 16384 + (h) * 8192 + ch0 * 512; \
    async_copy16(_d,       Ws0 + (size_t)(h) * HALF + (size_t)(st) * 64); \
    async_copy16(_d + 512, Ws1 + (size_t)(h) * HALF + (size_t)(st) * 64); \
  } while (0)

#define PHASE(tt, MQ, NQ, DOA, DOB, STAGE_STMT, VMC) do { \
    const unsigned short* Ab = sh + ((tt) & 1) * 32768; \
    const unsigned short* Bb = Ab + 16384; \
    if (DOA) { \
      _Pragma("unroll") \
      for (int ii = 0; ii < 4; ++ii) { \
        af[ii][0] = *(const bf16x8*)&Ab[(2 * (4 * (MQ) + ii) + wr) * 1024 + aoff0]; \
        af[ii][1] = *(const bf16x8*)&Ab[(2 * (4 * (MQ) + ii) + wr) * 1024 + aoff1]; \
      } \
    } \
    if (DOB) { \
      _Pragma("unroll") \
      for (int jj = 0; jj < 2; ++jj) { \
        bq[NQ][jj][0] = *(const bf16x8*)&Bb[(4 * (2 * (NQ) + jj) + wc) * 1024 + boff0]; \
        bq[NQ][jj][1] = *(const bf16x8*)&Bb[(4 * (2 * (NQ) + jj) + wc) * 1024 + boff1]; \
      } \
    } \
    STAGE_STMT; \
    asm volatile("s_waitcnt vmcnt(" #VMC ")" ::: "memory"); \
    __builtin_amdgcn_s_barrier(); \
    __builtin_amdgcn_s_setprio(1); \
    _Pragma("unroll") \
    for (int ii = 0; ii < 4; ++ii) \
      _Pragma("unroll") \
      for (int jj = 0; jj < 2; ++jj) { \
        acc[4*(MQ)+ii][2*(NQ)+jj] = __builtin_amdgcn_mfma_f32_16x16x32_bf16(af[ii][0], bq[NQ][jj][0], acc[4*(MQ)+ii][2*(NQ)+jj], 0, 0, 0); \
        acc[4*(MQ)+ii][2*(NQ)+jj] = __builtin_amdgcn_mfma_f32_16x16x32_bf16(af[ii][1], bq[NQ][jj][1], acc[4*(MQ)+ii][2*(NQ)+jj], 0, 0, 0); \
      } \
    __builtin_amdgcn_s_setprio(0); \
    __builtin_amdgcn_s_barrier(); \
    __builtin_amdgcn_sched_barrier(0); \
  } while (0)

  // ---- prologue: 6 units in read order; vmcnt(8) retires X(0,0), W(0,0) ----
  STAGE_X(0, 0); STAGE_W(0, 0); STAGE_W(0, 1); STAGE_X(0, 1);
  STAGE_X(1, 0); STAGE_W(1, 0);
  asm volatile("s_waitcnt vmcnt(8)" ::: "memory");
  __builtin_amdgcn_s_barrier();

  // ---- main loop: iterations 0..30, uniform staging ----
  for (int i = 0; i < K_TILES / 2 - 1; ++i) {
    const int u = 2 * i, v = 2 * i + 1;
    PHASE(u, 0, 0, 1, 1, { STAGE_W(v, 1); },     8);
    PHASE(u, 0, 1, 0, 1, { STAGE_X(v, 1); },     8);
    PHASE(u, 1, 1, 1, 0, { STAGE_X(u + 2, 0); }, 8);
    PHASE(u, 1, 0, 0, 0, { STAGE_W(u + 2, 0); }, 8);
    PHASE(v, 0, 0, 1, 1, { STAGE_W(u + 2, 1); }, 8);
    PHASE(v, 0, 1, 0, 1, { STAGE_X(u + 2, 1); }, 8);
    PHASE(v, 1, 1, 1, 0, { STAGE_X(v + 2, 0); }, 8);
    PHASE(v, 1, 0, 0, 0, { STAGE_W(v + 2, 0); }, 8);
  }

  // ---- peeled last iteration (u=62, v=63): graded drain 8,8,8,4,2,0,0,0 ----
  {
    const int u = K_TILES - 2, v = K_TILES - 1;
    PHASE(u, 0, 0, 1, 1, { STAGE_W(v, 1); }, 8);
    PHASE(u, 0, 1, 0, 1, { STAGE_X(v, 1); }, 8);
    PHASE(u, 1, 1, 1, 0, {},                 8);
    PHASE(u, 1, 0, 0, 0, {},                 4);
    PHASE(v, 0, 0, 1, 1, {},                 2);
    PHASE(v, 0, 1, 0, 1, {},                 0);
    PHASE(v, 1, 1, 1, 0, {},                 0);
    PHASE(v, 1, 0, 0, 0, {},                 0);
  }

  // ---- epilogue: scale + bias, store f32 ----
  // C/D layout (m89): col = lane&15, row = (lane>>4)*4 + e
  const int erow = (lane >> 4) * 4;
  const int ecol = lane & 15;
  #pragma unroll
  for (int j = 0; j < 4; ++j) {
    const int ocol = col0 + (4 * j + wc) * 16 + ecol;
    const float s  = S[ocol];
    const float bb = Bv[ocol];
    #pragma unroll
    for (int ii = 0; ii < 8; ++ii) {
      const int orow = row0 + (2 * ii + wr) * 16 + erow;
      #pragma unroll
      for (int e = 0; e < 4; ++e)
        O[(size_t)(orow + e) * N_DIM + ocol] = acc[ii][j][e] * s + bb;
    }
  }
#undef PHASE
#undef STAGE_X
#undef STAGE_W
}

// ---------------- fallback (round-3 kernel, verified) ----------------
#define FB_BM 128
#define FB_BK 32
#define PITCH 40
__global__ __launch_bounds__(256)
void w8a16_fallback_kernel(const float* __restrict__ X, const int* __restrict__ W,
                           const float* __restrict__ S, const float* __restrict__ Bv,
                           float* __restrict__ O)
{
  __shared__ unsigned short As[FB_BM * PITCH];
  __shared__ unsigned short Bs[FB_BM * PITCH];
  const int tid = threadIdx.x, lane = tid & 63, wid = tid >> 6;
  const int wr = wid >> 1, wc = wid & 1;
  const int p = blockIdx.x, xcd = p & 7, seq = p >> 3;
  const int bn_idx = seq >> 3, by_idx = xcd * 8 + (seq & 7);
  const int row0 = by_idx * FB_BM, col0 = bn_idx * FB_BM;
  f32x4 acc[4][4] = {};
  const int st_row = tid >> 1, st_kc = (tid & 1) * 16;
  const float* xsrc = X + (size_t)(row0 + st_row) * K_DIM + st_kc;
  const int*   wsrc = W + (size_t)(col0 + st_row) * K_DIM + st_kc;
  unsigned short* adst = &As[st_row * PITCH + st_kc];
  unsigned short* bdst = &Bs[st_row * PITCH + st_kc];
  const int fr = lane & 15, fk = (lane >> 4) * 8;
  for (int kt = 0; kt < K_DIM; kt += FB_BK) {
    f32x4 a0 = *(const f32x4*)(xsrc + kt);
    f32x4 a1 = *(const f32x4*)(xsrc + kt + 4);
    f32x4 a2 = *(const f32x4*)(xsrc + kt + 8);
    f32x4 a3 = *(const f32x4*)(xsrc + kt + 12);
    i32x4 w0 = *(const i32x4*)(wsrc + kt);
    i32x4 w1 = *(const i32x4*)(wsrc + kt + 4);
    i32x4 w2 = *(const i32x4*)(wsrc + kt + 8);
    i32x4 w3 = *(const i32x4*)(wsrc + kt + 12);
    u16x8 pa0, pa1, pb0, pb1;
    #pragma unroll
    for (int e = 0; e < 4; ++e) {
      pa0[e] = f2bf_rne(a0[e]); pa0[e+4] = f2bf_rne(a1[e]);
      pa1[e] = f2bf_rne(a2[e]); pa1[e+4] = f2bf_rne(a3[e]);
      pb0[e] = i2bf(w0[e]);     pb0[e+4] = i2bf(w1[e]);
      pb1[e] = i2bf(w2[e]);     pb1[e+4] = i2bf(w3[e]);
    }
    __syncthreads();
    *(u16x8*)(adst) = pa0; *(u16x8*)(adst + 8) = pa1;
    *(u16x8*)(bdst) = pb0; *(u16x8*)(bdst + 8) = pb1;
    __syncthreads();
    bf16x8 af[4], bfr[4];
    #pragma unroll
    for (int i = 0; i < 4; ++i)
      af[i] = *(const bf16x8*)&As[(wr * 64 + i * 16 + fr) * PITCH + fk];
    #pragma unroll
    for (int j = 0; j < 4; ++j)
      bfr[j] = *(const bf16x8*)&Bs[(wc * 64 + j * 16 + fr) * PITCH + fk];
    #pragma unroll
    for (int i = 0; i < 4; ++i)
      #pragma unroll
      for (int j = 0; j < 4; ++j)
        acc[i][j] = __builtin_amdgcn_mfma_f32_16x16x32_bf16(af[i], bfr[j], acc[i][j], 0, 0, 0);
  }
  const int erow = (lane >> 4) * 4, ecol = lane & 15;
  #pragma unroll
  for (int j = 0; j < 4; ++j) {
    const int col = col0 + wc * 64 + j * 16 + ecol;
    const float s = S[col], bb = Bv[col];
    #pragma unroll
    for (int i = 0; i < 4; ++i) {
      const int rbase = row0 + wr * 64 + i * 16 + erow;
      #pragma unroll
      for (int e = 0; e < 4; ++e)
        O[(size_t)(rbase + e) * N_DIM + col] = acc[i][j][e] * s + bb;
    }
  }
}

extern "C" void kernel_launch(void* const* d_in, const int* in_sizes, int n_in,
                              void* d_out, int out_size, void* d_ws, size_t ws_size,
                              hipStream_t stream) {
  const float* x  = (const float*)d_in[0];
  const int*   w  = (const int*)d_in[1];
  const float* sc = (const float*)d_in[2];
  const float* bi = (const float*)d_in[3];
  float* out = (float*)d_out;

  const size_t w_elems = (size_t)N_DIM * K_DIM;
  const size_t x_elems = (size_t)M_DIM * K_DIM;
  const size_t need = (w_elems + x_elems) * sizeof(unsigned short);

  if (ws_size >= need) {
    unsigned short* Wb = (unsigned short*)d_ws;
    unsigned short* Xb = Wb + w_elems;
    dequant_w_kernel<<<2048, 256, 0, stream>>>(w, Wb);
    conv_x_kernel<<<2048, 256, 0, stream>>>(x, Xb);
    const int grid = (M_DIM / 256) * (N_DIM / 256);  // 32 * 43 = 1376
    w8a16_main_kernel<<<grid, 512, 0, stream>>>(Xb, Wb, sc, bi, out);
  } else {
    const int grid = (M_DIM / FB_BM) * (N_DIM / FB_BM);
    w8a16_fallback_kernel<<<grid, 256, 0, stream>>>(x, w, sc, bi, out);
  }
}